// Round 1
// baseline (941.489 us; speedup 1.0000x reference)
//
#include <hip/hip_runtime.h>

#define N_NODES 100000
#define N_EDGES 1600000
#define ET      (N_EDGES + N_NODES)   // edges + self-loops = 1,700,000
#define IN_CH   64
#define HIDC    16
#define HEADS   4
#define C1      (HEADS * HIDC)        // 64
#define NG      512
#define SLOPE   0.2f

// ---------------- layer 1: h1 = x @ W1, attention logits ----------------
__global__ __launch_bounds__(256) void k_h1(
    const float* __restrict__ x, const float* __restrict__ W1,
    const float* __restrict__ a1s, const float* __restrict__ a1d,
    float* __restrict__ h1, float* __restrict__ al1s, float* __restrict__ al1d)
{
    __shared__ float Wl[64 * 64];
    __shared__ float xs[4][64];
    __shared__ float hs[4][64];
    int tid = threadIdx.x;
    for (int i = tid; i < 64 * 64; i += 256) Wl[i] = W1[i];
    int n = tid >> 6, c = tid & 63;
    int node = blockIdx.x * 4 + n;
    if (node < N_NODES) xs[n][c] = x[node * 64 + c];
    __syncthreads();
    if (node < N_NODES) {
        float acc = 0.f;
#pragma unroll
        for (int k = 0; k < 64; ++k) acc = fmaf(xs[n][k], Wl[k * 64 + c], acc);
        h1[node * 64 + c] = acc;
        hs[n][c] = acc;
    }
    __syncthreads();
    if (tid < 16) {
        int n2 = tid >> 2, h = tid & 3;
        int node2 = blockIdx.x * 4 + n2;
        if (node2 < N_NODES) {
            float s = 0.f, d = 0.f;
#pragma unroll
            for (int j = 0; j < 16; ++j) {
                float v = hs[n2][h * 16 + j];
                s = fmaf(v, a1s[h * 16 + j], s);
                d = fmaf(v, a1d[h * 16 + j], d);
            }
            al1s[node2 * 4 + h] = s;
            al1d[node2 * 4 + h] = d;
        }
    }
}

// ---------------- layer 1: edge scatter (64 lanes / edge) ----------------
__global__ __launch_bounds__(256) void k_edge1(
    const int* __restrict__ ei, const float* __restrict__ h1,
    const float* __restrict__ al1s, const float* __restrict__ al1d,
    float* __restrict__ agg1, float* __restrict__ den1)
{
    int tid = threadIdx.x;
    long long gid = (long long)blockIdx.x * 256 + tid;
    int eid = (int)(gid >> 6);
    int c = tid & 63;
    if (eid >= ET) return;
    int s, d;
    if (eid < N_EDGES) { s = ei[eid]; d = ei[N_EDGES + eid]; }
    else               { s = eid - N_EDGES; d = s; }
    int h = c >> 4;
    float e = al1s[s * 4 + h] + al1d[d * 4 + h];
    e = e > 0.f ? e : SLOPE * e;
    float w = __expf(e);
    atomicAdd(&agg1[d * 64 + c], w * h1[s * 64 + c]);
    if ((c & 15) == 0) atomicAdd(&den1[d * 4 + h], w);
}

// ------- layer 1 finish (norm+bias+ELU) fused with layer 2 linear -------
__global__ __launch_bounds__(256) void k_node1(
    const float* __restrict__ agg1, const float* __restrict__ den1,
    const float* __restrict__ b1, const float* __restrict__ W2,
    const float* __restrict__ a2s, const float* __restrict__ a2d,
    float* __restrict__ h2, float* __restrict__ al2s, float* __restrict__ al2d)
{
    __shared__ float W2l[64 * 16];
    __shared__ float h1b[4][64];
    __shared__ float h2s[4][16];
    int tid = threadIdx.x;
    for (int i = tid; i < 64 * 16; i += 256) W2l[i] = W2[i];
    int n = tid >> 6, c = tid & 63;
    int node = blockIdx.x * 4 + n;
    if (node < N_NODES) {
        float v = agg1[node * 64 + c] / (den1[node * 4 + (c >> 4)] + 1e-16f) + b1[c];
        v = v > 0.f ? v : expm1f(v);   // ELU
        h1b[n][c] = v;
    }
    __syncthreads();
    if (c < 16 && node < N_NODES) {
        float acc = 0.f;
#pragma unroll
        for (int k = 0; k < 64; ++k) acc = fmaf(h1b[n][k], W2l[k * 16 + c], acc);
        h2[node * 16 + c] = acc;
        h2s[n][c] = acc;
    }
    __syncthreads();
    if (c == 0 && node < N_NODES) {
        float s = 0.f, dd = 0.f;
#pragma unroll
        for (int j = 0; j < 16; ++j) {
            float v = h2s[n][j];
            s = fmaf(v, a2s[j], s);
            dd = fmaf(v, a2d[j], dd);
        }
        al2s[node] = s;
        al2d[node] = dd;
    }
}

// ---------------- layer 2: edge scatter (16 lanes / edge) ----------------
__global__ __launch_bounds__(256) void k_edge2(
    const int* __restrict__ ei, const float* __restrict__ h2,
    const float* __restrict__ al2s, const float* __restrict__ al2d,
    float* __restrict__ agg2, float* __restrict__ den2)
{
    int tid = threadIdx.x;
    long long gid = (long long)blockIdx.x * 256 + tid;
    int eid = (int)(gid >> 4);
    int c = tid & 15;
    if (eid >= ET) return;
    int s, d;
    if (eid < N_EDGES) { s = ei[eid]; d = ei[N_EDGES + eid]; }
    else               { s = eid - N_EDGES; d = s; }
    float e = al2s[s] + al2d[d];
    e = e > 0.f ? e : SLOPE * e;
    float w = __expf(e);
    atomicAdd(&agg2[d * 16 + c], w * h2[s * 16 + c]);
    if (c == 0) atomicAdd(&den2[d], w);
}

// -------- layer 2 finish (norm+bias+ELU) + mean-pool accumulation --------
__global__ __launch_bounds__(256) void k_node2(
    const float* __restrict__ agg2, const float* __restrict__ den2,
    const float* __restrict__ b2, const int* __restrict__ batch,
    float* __restrict__ pooled, float* __restrict__ counts)
{
    int tid = threadIdx.x;
    long long gid = (long long)blockIdx.x * 256 + tid;
    int node = (int)(gid >> 4);
    int c = tid & 15;
    if (node >= N_NODES) return;
    float v = agg2[node * 16 + c] / (den2[node] + 1e-16f) + b2[c];
    v = v > 0.f ? v : expm1f(v);   // ELU
    int g = batch[node];
    atomicAdd(&pooled[g * 16 + c], v);
    if (c == 0) atomicAdd(&counts[g], 1.0f);
}

// ---------------- final: mean + linear classifier ----------------
__global__ __launch_bounds__(256) void k_final(
    const float* __restrict__ pooled, const float* __restrict__ counts,
    const float* __restrict__ Wc, const float* __restrict__ bc,
    float* __restrict__ out)
{
    int g = blockIdx.x * 256 + threadIdx.x;
    if (g >= NG) return;
    float cnt = fmaxf(counts[g], 1.0f);
    float acc = 0.f;
#pragma unroll
    for (int c = 0; c < 16; ++c) acc = fmaf(pooled[g * 16 + c] / cnt, Wc[c], acc);
    out[g] = acc + bc[0];
}

extern "C" void kernel_launch(void* const* d_in, const int* in_sizes, int n_in,
                              void* d_out, int out_size, void* d_ws, size_t ws_size,
                              hipStream_t stream)
{
    const float* x    = (const float*)d_in[0];
    const int*   ei   = (const int*)d_in[1];
    const int*   batc = (const int*)d_in[2];
    const float* W1   = (const float*)d_in[3];
    const float* a1s  = (const float*)d_in[4];
    const float* a1d  = (const float*)d_in[5];
    const float* b1   = (const float*)d_in[6];
    const float* W2   = (const float*)d_in[7];
    const float* a2s  = (const float*)d_in[8];
    const float* a2d  = (const float*)d_in[9];
    const float* b2   = (const float*)d_in[10];
    const float* Wc   = (const float*)d_in[11];
    const float* bc   = (const float*)d_in[12];
    float* out = (float*)d_out;

    // ---- workspace carve (floats). Zero-init region first, one memset. ----
    float* ws = (float*)d_ws;
    size_t off = 0;
    float* agg1   = ws + off; off += (size_t)N_NODES * 64;   // 6.4M
    float* den1   = ws + off; off += (size_t)N_NODES * 4;    // 0.4M
    float* agg2   = ws + off; off += (size_t)N_NODES * 16;   // 1.6M
    float* den2   = ws + off; off += (size_t)N_NODES;        // 0.1M
    float* pooled = ws + off; off += (size_t)NG * 16;
    float* counts = ws + off; off += (size_t)NG;
    size_t zero_floats = off;
    float* h1   = ws + off; off += (size_t)N_NODES * 64;
    float* al1s = ws + off; off += (size_t)N_NODES * 4;
    float* al1d = ws + off; off += (size_t)N_NODES * 4;
    float* h2   = ws + off; off += (size_t)N_NODES * 16;
    float* al2s = ws + off; off += (size_t)N_NODES;
    float* al2d = ws + off; off += (size_t)N_NODES;

    hipMemsetAsync(d_ws, 0, zero_floats * sizeof(float), stream);

    k_h1<<<(N_NODES + 3) / 4, 256, 0, stream>>>(x, W1, a1s, a1d, h1, al1s, al1d);
    k_edge1<<<((long long)ET * 64 + 255) / 256, 256, 0, stream>>>(ei, h1, al1s, al1d, agg1, den1);
    k_node1<<<(N_NODES + 3) / 4, 256, 0, stream>>>(agg1, den1, b1, W2, a2s, a2d, h2, al2s, al2d);
    k_edge2<<<((long long)ET * 16 + 255) / 256, 256, 0, stream>>>(ei, h2, al2s, al2d, agg2, den2);
    k_node2<<<((long long)N_NODES * 16 + 255) / 256, 256, 0, stream>>>(agg2, den2, b2, batc, pooled, counts);
    k_final<<<(NG + 255) / 256, 256, 0, stream>>>(pooled, counts, Wc, bc, out);
}

// Round 2
// 777.344 us; speedup vs baseline: 1.2112x; 1.2112x over previous
//
#include <hip/hip_runtime.h>

#define N_NODES 100000
#define N_EDGES 1600000
#define ET      (N_EDGES + N_NODES)   // edges + self-loops = 1,700,000
#define NG      512
#define SLOPE   0.2f
#define NB_SCAN ((N_NODES + 511) / 512)   // 196 scan blocks

// ---------------- layer 1: h1 = x @ W1, attention logits ----------------
__global__ __launch_bounds__(256) void k_h1(
    const float* __restrict__ x, const float* __restrict__ W1,
    const float* __restrict__ a1s, const float* __restrict__ a1d,
    float* __restrict__ h1, float* __restrict__ al1s, float* __restrict__ al1d)
{
    __shared__ float Wl[64 * 64];
    __shared__ float xs[4][64];
    __shared__ float hs[4][64];
    int tid = threadIdx.x;
    for (int i = tid; i < 64 * 64; i += 256) Wl[i] = W1[i];
    int n = tid >> 6, c = tid & 63;
    int node = blockIdx.x * 4 + n;
    xs[n][c] = x[node * 64 + c];
    __syncthreads();
    float acc = 0.f;
#pragma unroll
    for (int k = 0; k < 64; ++k) acc = fmaf(xs[n][k], Wl[k * 64 + c], acc);
    h1[node * 64 + c] = acc;
    hs[n][c] = acc;
    __syncthreads();
    if (tid < 16) {
        int n2 = tid >> 2, h = tid & 3;
        int node2 = blockIdx.x * 4 + n2;
        float s = 0.f, d = 0.f;
#pragma unroll
        for (int j = 0; j < 16; ++j) {
            float v = hs[n2][h * 16 + j];
            s = fmaf(v, a1s[h * 16 + j], s);
            d = fmaf(v, a1d[h * 16 + j], d);
        }
        al1s[node2 * 4 + h] = s;
        al1d[node2 * 4 + h] = d;
    }
}

// ---------------- CSR build: histogram of dst degrees ----------------
__global__ __launch_bounds__(256) void k_hist(const int* __restrict__ ei, int* __restrict__ deg)
{
    int eid = blockIdx.x * 256 + threadIdx.x;
    if (eid >= ET) return;
    int d = (eid < N_EDGES) ? ei[N_EDGES + eid] : (eid - N_EDGES);
    atomicAdd(&deg[d], 1);
}

// ---- exclusive scan over deg (512-wide blocks, Hillis-Steele) ----
__global__ __launch_bounds__(512) void k_scan1(const int* __restrict__ deg,
                                               int* __restrict__ part, int* __restrict__ bsum)
{
    __shared__ int tmp[512];
    int i = blockIdx.x * 512 + threadIdx.x;
    int v = (i < N_NODES) ? deg[i] : 0;
    tmp[threadIdx.x] = v;
    __syncthreads();
    for (int off = 1; off < 512; off <<= 1) {
        int t = (threadIdx.x >= off) ? tmp[threadIdx.x - off] : 0;
        __syncthreads();
        tmp[threadIdx.x] += t;
        __syncthreads();
    }
    if (i < N_NODES) part[i] = tmp[threadIdx.x] - v;   // exclusive
    if (threadIdx.x == 511) bsum[blockIdx.x] = tmp[511];
}

__global__ __launch_bounds__(256) void k_scan2(int* __restrict__ bsum)
{
    __shared__ int tmp[256];
    int tid = threadIdx.x;
    int v = (tid < NB_SCAN) ? bsum[tid] : 0;
    tmp[tid] = v;
    __syncthreads();
    for (int off = 1; off < 256; off <<= 1) {
        int t = (tid >= off) ? tmp[tid - off] : 0;
        __syncthreads();
        tmp[tid] += t;
        __syncthreads();
    }
    if (tid < NB_SCAN) bsum[tid] = tmp[tid] - v;       // exclusive
}

__global__ __launch_bounds__(512) void k_scan3(const int* __restrict__ part,
                                               const int* __restrict__ bsum,
                                               int* __restrict__ offs, int* __restrict__ cursor)
{
    int i = blockIdx.x * 512 + threadIdx.x;
    if (i >= N_NODES) return;
    int o = part[i] + bsum[blockIdx.x];
    offs[i] = o;
    cursor[i] = o;
}

// ---------------- CSR build: scatter src by dst ----------------
__global__ __launch_bounds__(256) void k_scatter(const int* __restrict__ ei,
                                                 int* __restrict__ cursor, int* __restrict__ csr)
{
    int eid = blockIdx.x * 256 + threadIdx.x;
    if (eid >= ET) return;
    int s, d;
    if (eid < N_EDGES) { s = ei[eid]; d = ei[N_EDGES + eid]; }
    else               { s = eid - N_EDGES; d = s; }
    int pos = atomicAdd(&cursor[d], 1);
    csr[pos] = s;
}

// ---- layer 1 aggregate (1 wave / dst) + norm+bias+ELU + layer-2 linear + logits ----
__global__ __launch_bounds__(256) void k_agg1(
    const int* __restrict__ offs, const int* __restrict__ deg, const int* __restrict__ csr,
    const float* __restrict__ h1, const float* __restrict__ al1s, const float* __restrict__ al1d,
    const float* __restrict__ b1, const float* __restrict__ W2,
    const float* __restrict__ a2s, const float* __restrict__ a2d,
    float* __restrict__ h2, float* __restrict__ al2s, float* __restrict__ al2d)
{
    __shared__ float W2l[64 * 16];
    __shared__ float h1b[4][64];
    __shared__ float h2s[4][16];
    int tid = threadIdx.x;
    for (int i = tid; i < 64 * 16; i += 256) W2l[i] = W2[i];
    int n = tid >> 6, c = tid & 63, h = c >> 4;
    int node = blockIdx.x * 4 + n;
    int st = offs[node], dg = deg[node];
    float ald = al1d[node * 4 + h];
    float acc = 0.f, den = 0.f;
    for (int j = 0; j < dg; ++j) {
        int s = csr[st + j];
        float e = al1s[s * 4 + h] + ald;
        e = e > 0.f ? e : SLOPE * e;
        float w = __expf(e);
        acc = fmaf(w, h1[s * 64 + c], acc);
        den += w;                       // identical across a head's 16 lanes
    }
    float v = acc / (den + 1e-16f) + b1[c];
    v = v > 0.f ? v : expm1f(v);        // ELU
    h1b[n][c] = v;
    __syncthreads();
    if (c < 16) {
        float a = 0.f;
#pragma unroll
        for (int k = 0; k < 64; ++k) a = fmaf(h1b[n][k], W2l[k * 16 + c], a);
        h2[node * 16 + c] = a;
        h2s[n][c] = a;
    }
    __syncthreads();
    if (c == 0) {
        float s2 = 0.f, d2 = 0.f;
#pragma unroll
        for (int j = 0; j < 16; ++j) {
            float v2 = h2s[n][j];
            s2 = fmaf(v2, a2s[j], s2);
            d2 = fmaf(v2, a2d[j], d2);
        }
        al2s[node] = s2;
        al2d[node] = d2;
    }
}

// ---- layer 2 aggregate (1 wave / dst, 4 edges x 16 ch) + norm+ELU + mean-pool ----
__global__ __launch_bounds__(256) void k_agg2(
    const int* __restrict__ offs, const int* __restrict__ deg, const int* __restrict__ csr,
    const float* __restrict__ h2, const float* __restrict__ al2s, const float* __restrict__ al2d,
    const float* __restrict__ b2, const int* __restrict__ batch,
    float* __restrict__ pooled, float* __restrict__ counts)
{
    int tid = threadIdx.x;
    int node = blockIdx.x * 4 + (tid >> 6);
    int lane = tid & 63;
    int sub = lane >> 4, c = lane & 15;
    int st = offs[node], dg = deg[node];
    float ald = al2d[node];
    float acc = 0.f, den = 0.f;
    for (int j = sub; j < dg; j += 4) {
        int s = csr[st + j];
        float e = al2s[s] + ald;
        e = e > 0.f ? e : SLOPE * e;
        float w = __expf(e);
        acc = fmaf(w, h2[s * 16 + c], acc);
        den += w;
    }
    acc += __shfl_xor(acc, 16); acc += __shfl_xor(acc, 32);
    den += __shfl_xor(den, 16); den += __shfl_xor(den, 32);
    if (sub == 0) {
        float v = acc / (den + 1e-16f) + b2[c];
        v = v > 0.f ? v : expm1f(v);    // ELU
        int g = batch[node];
        atomicAdd(&pooled[g * 16 + c], v);
        if (c == 0) atomicAdd(&counts[g], 1.0f);
    }
}

// ---------------- final: mean + linear classifier ----------------
__global__ __launch_bounds__(256) void k_final(
    const float* __restrict__ pooled, const float* __restrict__ counts,
    const float* __restrict__ Wc, const float* __restrict__ bc,
    float* __restrict__ out)
{
    int g = blockIdx.x * 256 + threadIdx.x;
    if (g >= NG) return;
    float cnt = fmaxf(counts[g], 1.0f);
    float acc = 0.f;
#pragma unroll
    for (int c = 0; c < 16; ++c) acc = fmaf(pooled[g * 16 + c] / cnt, Wc[c], acc);
    out[g] = acc + bc[0];
}

extern "C" void kernel_launch(void* const* d_in, const int* in_sizes, int n_in,
                              void* d_out, int out_size, void* d_ws, size_t ws_size,
                              hipStream_t stream)
{
    const float* x    = (const float*)d_in[0];
    const int*   ei   = (const int*)d_in[1];
    const int*   batc = (const int*)d_in[2];
    const float* W1   = (const float*)d_in[3];
    const float* a1s  = (const float*)d_in[4];
    const float* a1d  = (const float*)d_in[5];
    const float* b1   = (const float*)d_in[6];
    const float* W2   = (const float*)d_in[7];
    const float* a2s  = (const float*)d_in[8];
    const float* a2d  = (const float*)d_in[9];
    const float* b2   = (const float*)d_in[10];
    const float* Wc   = (const float*)d_in[11];
    const float* bc   = (const float*)d_in[12];
    float* out = (float*)d_out;

    // ---- workspace carve (all 4-byte elems). Zero region first, one memset. ----
    char* ws = (char*)d_ws;
    size_t off = 0;
    auto carve = [&](size_t elems) { void* p = ws + off; off += elems * 4; return p; };
    int*   deg    = (int*)  carve(N_NODES);        // zeroed
    float* pooled = (float*)carve((size_t)NG * 16);// zeroed
    float* counts = (float*)carve(NG);             // zeroed
    size_t zero_bytes = off;
    int*   part   = (int*)  carve(N_NODES);
    int*   bsum   = (int*)  carve(256);
    int*   offs   = (int*)  carve(N_NODES);
    int*   cursor = (int*)  carve(N_NODES);
    int*   csr    = (int*)  carve(ET);
    float* h1     = (float*)carve((size_t)N_NODES * 64);
    float* al1s   = (float*)carve((size_t)N_NODES * 4);
    float* al1d   = (float*)carve((size_t)N_NODES * 4);
    float* h2     = (float*)carve((size_t)N_NODES * 16);
    float* al2s   = (float*)carve(N_NODES);
    float* al2d   = (float*)carve(N_NODES);

    hipMemsetAsync(d_ws, 0, zero_bytes, stream);

    k_h1     <<<N_NODES / 4, 256, 0, stream>>>(x, W1, a1s, a1d, h1, al1s, al1d);
    k_hist   <<<(ET + 255) / 256, 256, 0, stream>>>(ei, deg);
    k_scan1  <<<NB_SCAN, 512, 0, stream>>>(deg, part, bsum);
    k_scan2  <<<1, 256, 0, stream>>>(bsum);
    k_scan3  <<<NB_SCAN, 512, 0, stream>>>(part, bsum, offs, cursor);
    k_scatter<<<(ET + 255) / 256, 256, 0, stream>>>(ei, cursor, csr);
    k_agg1   <<<N_NODES / 4, 256, 0, stream>>>(offs, deg, csr, h1, al1s, al1d,
                                               b1, W2, a2s, a2d, h2, al2s, al2d);
    k_agg2   <<<N_NODES / 4, 256, 0, stream>>>(offs, deg, csr, h2, al2s, al2d,
                                               b2, batc, pooled, counts);
    k_final  <<<(NG + 255) / 256, 256, 0, stream>>>(pooled, counts, Wc, bc, out);
}

// Round 3
// 644.384 us; speedup vs baseline: 1.4611x; 1.2063x over previous
//
#include <hip/hip_runtime.h>

#define N_NODES 100000
#define N_EDGES 1600000
#define ET      (N_EDGES + N_NODES)   // edges + self-loops = 1,700,000
#define NG      512
#define SLOPE   0.2f
#define NB_SCAN ((N_NODES + 511) / 512)   // 196 scan blocks

// ---------------- layer 1: h1 = x @ W1, attention logits ----------------
__global__ __launch_bounds__(256) void k_h1(
    const float* __restrict__ x, const float* __restrict__ W1,
    const float* __restrict__ a1s, const float* __restrict__ a1d,
    float* __restrict__ h1, float* __restrict__ al1s, float* __restrict__ al1d)
{
    __shared__ float Wl[64 * 64];
    __shared__ float xs[4][64];
    __shared__ float hs[4][64];
    int tid = threadIdx.x;
    for (int i = tid; i < 64 * 64; i += 256) Wl[i] = W1[i];
    int n = tid >> 6, c = tid & 63;
    int node = blockIdx.x * 4 + n;
    xs[n][c] = x[node * 64 + c];
    __syncthreads();
    float acc = 0.f;
#pragma unroll
    for (int k = 0; k < 64; ++k) acc = fmaf(xs[n][k], Wl[k * 64 + c], acc);
    h1[node * 64 + c] = acc;
    hs[n][c] = acc;
    __syncthreads();
    if (tid < 16) {
        int n2 = tid >> 2, h = tid & 3;
        int node2 = blockIdx.x * 4 + n2;
        float s = 0.f, d = 0.f;
#pragma unroll
        for (int j = 0; j < 16; ++j) {
            float v = hs[n2][h * 16 + j];
            s = fmaf(v, a1s[h * 16 + j], s);
            d = fmaf(v, a1d[h * 16 + j], d);
        }
        al1s[node2 * 4 + h] = s;
        al1d[node2 * 4 + h] = d;
    }
}

// ---------------- CSR build ----------------
__global__ __launch_bounds__(256) void k_hist(const int* __restrict__ ei, int* __restrict__ deg)
{
    int eid = blockIdx.x * 256 + threadIdx.x;
    if (eid >= ET) return;
    int d = (eid < N_EDGES) ? ei[N_EDGES + eid] : (eid - N_EDGES);
    atomicAdd(&deg[d], 1);
}

__global__ __launch_bounds__(512) void k_scan1(const int* __restrict__ deg,
                                               int* __restrict__ part, int* __restrict__ bsum)
{
    __shared__ int tmp[512];
    int i = blockIdx.x * 512 + threadIdx.x;
    int v = (i < N_NODES) ? deg[i] : 0;
    tmp[threadIdx.x] = v;
    __syncthreads();
    for (int off = 1; off < 512; off <<= 1) {
        int t = (threadIdx.x >= off) ? tmp[threadIdx.x - off] : 0;
        __syncthreads();
        tmp[threadIdx.x] += t;
        __syncthreads();
    }
    if (i < N_NODES) part[i] = tmp[threadIdx.x] - v;
    if (threadIdx.x == 511) bsum[blockIdx.x] = tmp[511];
}

__global__ __launch_bounds__(256) void k_scan2(int* __restrict__ bsum)
{
    __shared__ int tmp[256];
    int tid = threadIdx.x;
    int v = (tid < NB_SCAN) ? bsum[tid] : 0;
    tmp[tid] = v;
    __syncthreads();
    for (int off = 1; off < 256; off <<= 1) {
        int t = (tid >= off) ? tmp[tid - off] : 0;
        __syncthreads();
        tmp[tid] += t;
        __syncthreads();
    }
    if (tid < NB_SCAN) bsum[tid] = tmp[tid] - v;
}

__global__ __launch_bounds__(512) void k_scan3(const int* __restrict__ part,
                                               const int* __restrict__ bsum,
                                               int* __restrict__ offs, int* __restrict__ cursor)
{
    int i = blockIdx.x * 512 + threadIdx.x;
    if (i >= N_NODES) return;
    int o = part[i] + bsum[blockIdx.x];
    offs[i] = o;
    cursor[i] = o;
}

__global__ __launch_bounds__(256) void k_scatter(const int* __restrict__ ei,
                                                 int* __restrict__ cursor, int* __restrict__ csr)
{
    int eid = blockIdx.x * 256 + threadIdx.x;
    if (eid >= ET) return;
    int s, d;
    if (eid < N_EDGES) { s = ei[eid]; d = ei[N_EDGES + eid]; }
    else               { s = eid - N_EDGES; d = s; }
    int pos = atomicAdd(&cursor[d], 1);
    csr[pos] = s;
}

// ---- layer 1 aggregate (1 wave/dst, MLP-friendly) + ELU + layer-2 linear + logits ----
__global__ __launch_bounds__(256) void k_agg1(
    const int* __restrict__ offs, const int* __restrict__ deg, const int* __restrict__ csr,
    const float* __restrict__ h1, const float* __restrict__ al1s, const float* __restrict__ al1d,
    const float* __restrict__ b1, const float* __restrict__ W2,
    const float* __restrict__ a2s, const float* __restrict__ a2d,
    float* __restrict__ h2, float* __restrict__ al2s, float* __restrict__ al2d)
{
    __shared__ float W2l[64 * 16];
    __shared__ int   sarr[4][64];
    __shared__ float warr[4][4 * 65];   // [wave][head*65 + j], padded: conflict-free
    __shared__ float h1b[4][64];
    __shared__ float h2s[4][16];
    int tid = threadIdx.x;
    for (int i = tid; i < 64 * 16; i += 256) W2l[i] = W2[i];
    __syncthreads();                    // only barrier: W2l is cross-wave

    int wv = tid >> 6, lane = tid & 63;
    int c = lane, h = lane >> 4;
    int node = blockIdx.x * 4 + wv;
    int st = offs[node], dg = deg[node];
    const float4 ald4 = *(const float4*)(al1d + node * 4);

    float acc = 0.f, den = 0.f;
    for (int base = 0; base < dg; base += 64) {
        int m = min(64, dg - base);
        if (lane < m) {
            int s = csr[st + base + lane];          // coalesced
            sarr[wv][lane] = s;
            const float4 as4 = *(const float4*)(al1s + s * 4);  // 16B gather
            float e0 = as4.x + ald4.x; e0 = e0 > 0.f ? e0 : SLOPE * e0;
            float e1 = as4.y + ald4.y; e1 = e1 > 0.f ? e1 : SLOPE * e1;
            float e2 = as4.z + ald4.z; e2 = e2 > 0.f ? e2 : SLOPE * e2;
            float e3 = as4.w + ald4.w; e3 = e3 > 0.f ? e3 : SLOPE * e3;
            warr[wv][0 * 65 + lane] = __expf(e0);
            warr[wv][1 * 65 + lane] = __expf(e1);
            warr[wv][2 * 65 + lane] = __expf(e2);
            warr[wv][3 * 65 + lane] = __expf(e3);
        }
        // intra-wave LDS dependency only — no barrier (trip counts diverge per wave)
#pragma unroll 4
        for (int j = 0; j < m; ++j) {
            int s = sarr[wv][j];                    // broadcast
            float wgt = warr[wv][h * 65 + j];       // broadcast per head
            acc = fmaf(wgt, h1[s * 64 + c], acc);   // 256B coalesced gather
            den += wgt;
        }
    }
    float v = acc / (den + 1e-16f) + b1[c];
    v = v > 0.f ? v : expm1f(v);        // ELU
    h1b[wv][c] = v;
    // intra-wave: no barrier needed
    if (c < 16) {
        float a = 0.f;
#pragma unroll
        for (int k = 0; k < 64; ++k) a = fmaf(h1b[wv][k], W2l[k * 16 + c], a);
        h2[node * 16 + c] = a;
        h2s[wv][c] = a;
    }
    if (c == 0) {
        float s2 = 0.f, d2 = 0.f;
#pragma unroll
        for (int j = 0; j < 16; ++j) {
            float v2 = h2s[wv][j];
            s2 = fmaf(v2, a2s[j], s2);
            d2 = fmaf(v2, a2d[j], d2);
        }
        al2s[node] = s2;
        al2d[node] = d2;
    }
}

// ---- layer 2 aggregate (1 wave/dst) + norm+ELU + mean-pool ----
__global__ __launch_bounds__(256) void k_agg2(
    const int* __restrict__ offs, const int* __restrict__ deg, const int* __restrict__ csr,
    const float* __restrict__ h2, const float* __restrict__ al2s, const float* __restrict__ al2d,
    const float* __restrict__ b2, const int* __restrict__ batch,
    float* __restrict__ pooled, float* __restrict__ counts)
{
    __shared__ int   sarr[4][64];
    __shared__ float warr[4][64];
    int tid = threadIdx.x;
    int wv = tid >> 6, lane = tid & 63;
    int sub = lane >> 4, c = lane & 15;
    int node = blockIdx.x * 4 + wv;
    int st = offs[node], dg = deg[node];
    float ald = al2d[node];

    float acc = 0.f, den = 0.f;
    for (int base = 0; base < dg; base += 64) {
        int m = min(64, dg - base);
        float wl = 0.f;
        if (lane < m) {
            int s = csr[st + base + lane];          // coalesced
            sarr[wv][lane] = s;
            float e = al2s[s] + ald;                // 64 independent gathers
            e = e > 0.f ? e : SLOPE * e;
            wl = __expf(e);
            warr[wv][lane] = wl;
        }
        // denominator: butterfly over the wave
        wl += __shfl_xor(wl, 1);  wl += __shfl_xor(wl, 2);
        wl += __shfl_xor(wl, 4);  wl += __shfl_xor(wl, 8);
        wl += __shfl_xor(wl, 16); wl += __shfl_xor(wl, 32);
        den += wl;
#pragma unroll 4
        for (int j = sub; j < m; j += 4) {
            int s = sarr[wv][j];                    // 16-lane broadcast
            float wgt = warr[wv][j];
            acc = fmaf(wgt, h2[s * 16 + c], acc);   // 64B gather x4 edges
        }
    }
    acc += __shfl_xor(acc, 16); acc += __shfl_xor(acc, 32);
    if (sub == 0) {
        float v = acc / (den + 1e-16f) + b2[c];
        v = v > 0.f ? v : expm1f(v);    // ELU
        int g = batch[node];
        atomicAdd(&pooled[g * 16 + c], v);
        if (c == 0) atomicAdd(&counts[g], 1.0f);
    }
}

// ---------------- final: mean + linear classifier ----------------
__global__ __launch_bounds__(256) void k_final(
    const float* __restrict__ pooled, const float* __restrict__ counts,
    const float* __restrict__ Wc, const float* __restrict__ bc,
    float* __restrict__ out)
{
    int g = blockIdx.x * 256 + threadIdx.x;
    if (g >= NG) return;
    float cnt = fmaxf(counts[g], 1.0f);
    float acc = 0.f;
#pragma unroll
    for (int c = 0; c < 16; ++c) acc = fmaf(pooled[g * 16 + c] / cnt, Wc[c], acc);
    out[g] = acc + bc[0];
}

extern "C" void kernel_launch(void* const* d_in, const int* in_sizes, int n_in,
                              void* d_out, int out_size, void* d_ws, size_t ws_size,
                              hipStream_t stream)
{
    const float* x    = (const float*)d_in[0];
    const int*   ei   = (const int*)d_in[1];
    const int*   batc = (const int*)d_in[2];
    const float* W1   = (const float*)d_in[3];
    const float* a1s  = (const float*)d_in[4];
    const float* a1d  = (const float*)d_in[5];
    const float* b1   = (const float*)d_in[6];
    const float* W2   = (const float*)d_in[7];
    const float* a2s  = (const float*)d_in[8];
    const float* a2d  = (const float*)d_in[9];
    const float* b2   = (const float*)d_in[10];
    const float* Wc   = (const float*)d_in[11];
    const float* bc   = (const float*)d_in[12];
    float* out = (float*)d_out;

    // ---- workspace carve, 16B-aligned chunks. Zero region first, one memset. ----
    char* ws = (char*)d_ws;
    size_t off = 0;
    auto carve = [&](size_t elems) {
        void* p = ws + off;
        off += ((elems * 4 + 15) & ~(size_t)15);
        return p;
    };
    int*   deg    = (int*)  carve(N_NODES);        // zeroed
    float* pooled = (float*)carve((size_t)NG * 16);// zeroed
    float* counts = (float*)carve(NG);             // zeroed
    size_t zero_bytes = off;
    int*   part   = (int*)  carve(N_NODES);
    int*   bsum   = (int*)  carve(256);
    int*   offs   = (int*)  carve(N_NODES);
    int*   cursor = (int*)  carve(N_NODES);
    int*   csr    = (int*)  carve(ET);
    float* h1     = (float*)carve((size_t)N_NODES * 64);
    float* al1s   = (float*)carve((size_t)N_NODES * 4);
    float* al1d   = (float*)carve((size_t)N_NODES * 4);
    float* h2     = (float*)carve((size_t)N_NODES * 16);
    float* al2s   = (float*)carve(N_NODES);
    float* al2d   = (float*)carve(N_NODES);

    hipMemsetAsync(d_ws, 0, zero_bytes, stream);

    k_h1     <<<N_NODES / 4, 256, 0, stream>>>(x, W1, a1s, a1d, h1, al1s, al1d);
    k_hist   <<<(ET + 255) / 256, 256, 0, stream>>>(ei, deg);
    k_scan1  <<<NB_SCAN, 512, 0, stream>>>(deg, part, bsum);
    k_scan2  <<<1, 256, 0, stream>>>(bsum);
    k_scan3  <<<NB_SCAN, 512, 0, stream>>>(part, bsum, offs, cursor);
    k_scatter<<<(ET + 255) / 256, 256, 0, stream>>>(ei, cursor, csr);
    k_agg1   <<<N_NODES / 4, 256, 0, stream>>>(offs, deg, csr, h1, al1s, al1d,
                                               b1, W2, a2s, a2d, h2, al2s, al2d);
    k_agg2   <<<N_NODES / 4, 256, 0, stream>>>(offs, deg, csr, h2, al2s, al2d,
                                               b2, batc, pooled, counts);
    k_final  <<<(NG + 255) / 256, 256, 0, stream>>>(pooled, counts, Wc, bc, out);
}